// Round 10
// baseline (217.115 us; speedup 1.0000x reference)
//
#include <hip/hip_runtime.h>
#include <cmath>

#define NCH   256
#define NPIX  3136
#define NB    32
#define SEV   7
#define INV_N (1.0f / 3136.0f)

typedef __attribute__((ext_vector_type(8)))  short bf16x8;
typedef __attribute__((ext_vector_type(4)))  float f32x4;
typedef __attribute__((ext_vector_type(16))) float f32x16;

// ws layout (float offsets)
#define KV7_F  (SEV * NB * 8 * 1024)   // 1,835,008
#define KM7_F  (SEV * NB * 256)        // 57,344
#define KVF_F  (NB * 8 * 1024)         // 262,144
#define KMF_F  (NB * 256)              // 8,192
#define KM7_OFF (KV7_F)
#define KVF_OFF (KM7_OFF + KM7_F)
#define KMF_OFF (KVF_OFF + KVF_F)
#define WF_OFF  (KMF_OFF + KMF_F)      // ushort region (16B aligned)

__device__ __forceinline__ ushort f2bf(float f) {
  unsigned u = __float_as_uint(f);
  u += 0x7FFFu + ((u >> 16) & 1u);
  return (ushort)(u >> 16);
}
__device__ __forceinline__ float bf2f(ushort h) {
  return __uint_as_float(((unsigned)h) << 16);
}

// ---------------------------------------------------------------------------
// Prep: qk_w (512x128) -> MFMA A-fragment layout, bf16 hi/lo split.
// ---------------------------------------------------------------------------
__global__ void wfrag_kernel(const float* __restrict__ qk_w, ushort* __restrict__ Wf) {
  const int tid = blockIdx.x * 512 + threadIdx.x;   // 0..16383
  const int lane = tid & 63;
  const int ks = (tid >> 6) & 3;
  const int mt = (tid >> 8) & 15;
  const int hl = (tid >> 12) & 1;
  const int side = (tid >> 13) & 1;
  const int ch = mt * 16 + (lane & 15);
  const int oc = side * 256 + ch;
  ushort v[8];
#pragma unroll
  for (int j = 0; j < 8; ++j) {
    const int k = ks * 32 + (lane >> 4) * 8 + j;
    const float w = qk_w[(size_t)oc * 128 + k];
    const ushort hi = f2bf(w);
    v[j] = (hl == 0) ? hi : f2bf(w - bf2f(hi));
  }
  *(uint4*)(Wf + (size_t)tid * 8) = *(const uint4*)v;
}

// ---------------------------------------------------------------------------
// Kernel A (restructured): wave h owns head h end-to-end.
//  - stage BOTH x halves to LDS bf16 [half][pos][ch] (reg-transposed, b64 writes)
//  - conv: K channels h*32..+32 over all 64 pos (2 mt x 4 nt x 4 ks x hi/lo)
//  - K kept wave-local in Kloc[pos][d] (packed b64 writes, no barrier)
//  - kv einsum 32x32x16: A=K (Kloc scalar reads), B=V (Xb scalar reads, 2-way)
//  - km fully in registers, one shfl-reduce at the end
// Grid 224: b = bid&31, sev = bid>>5. 512 threads, 2 blocks/CU.
// ---------------------------------------------------------------------------
__global__ __launch_bounds__(512, 4)
void kv_kernel(const float* __restrict__ x, const ushort* __restrict__ Wf,
               const float* __restrict__ qk_b, float* __restrict__ kv7,
               float* __restrict__ km7) {
  const int bid = blockIdx.x;
  const int b = bid & 31, sev = bid >> 5;
  const int t = threadIdx.x;
  const int h = t >> 6, l = t & 63;     // wave = head
  const int q = l >> 4, r15 = l & 15;   // conv frag coords
  const int e = l & 31, q5 = l >> 5;    // einsum coords

  __shared__ ushort Xb[2][64][136];     // [half][pos][ch-local] bf16, 34.8 KB
  __shared__ ushort Kloc[8][64][36];    // per-wave K [pos][d] bf16, 36.9 KB

  // resident W frags: side=1 (k-conv), mt = 2h + mt2
  bf16x8 wf[2][4][2];
#pragma unroll
  for (int mt2 = 0; mt2 < 2; ++mt2)
#pragma unroll
    for (int ks = 0; ks < 4; ++ks)
#pragma unroll
      for (int hl = 0; hl < 2; ++hl) {
        const size_t off =
            (size_t)(((((2 + hl) * 16 + (2 * h + mt2)) * 4 + ks) * 64 + l)) * 8;
        wf[mt2][ks][hl] = *(const bf16x8*)(Wf + off);
      }

  float bias[2][4];
#pragma unroll
  for (int mt2 = 0; mt2 < 2; ++mt2)
#pragma unroll
    for (int r = 0; r < 4; ++r)
      bias[mt2][r] = qk_b[256 + h * 32 + mt2 * 16 + q * 4 + r];

  f32x16 kvacc;
#pragma unroll
  for (int i = 0; i < 16; ++i) kvacc[i] = 0.f;
  float kmacc[2][4] = {{0.f, 0.f, 0.f, 0.f}, {0.f, 0.f, 0.f, 0.f}};

  const float* xsrc = x + (size_t)(b * NCH) * NPIX + sev * 448;

  for (int st = 0; st < SEV; ++st) {
    const int p0 = st * 64;
    __syncthreads();   // prev subtile's einsum done reading Xb

    // ---- stage all 256 channels x 64 pos: reg-transpose, b64 writes ----
#pragma unroll
    for (int rr = 0; rr < 2; ++rr) {
      const int id = t + 512 * rr;     // 0..1023
      const int chq = id >> 4;         // 4-ch group 0..63
      const int pq = id & 15;          // pos-quad
      const float* s = xsrc + (size_t)(chq * 4) * NPIX + p0 + pq * 4;
      const float4 va = *(const float4*)(s);
      const float4 vb = *(const float4*)(s + NPIX);
      const float4 vc = *(const float4*)(s + 2 * NPIX);
      const float4 vd = *(const float4*)(s + 3 * NPIX);
      const float ar[4] = {va.x, va.y, va.z, va.w};
      const float br[4] = {vb.x, vb.y, vb.z, vb.w};
      const float cr[4] = {vc.x, vc.y, vc.z, vc.w};
      const float dr[4] = {vd.x, vd.y, vd.z, vd.w};
      const int half = chq >> 5;
      const int chl = (chq & 31) * 4;
#pragma unroll
      for (int p = 0; p < 4; ++p) {
        const uint u0 = (uint)f2bf(ar[p]) | ((uint)f2bf(br[p]) << 16);
        const uint u1 = (uint)f2bf(cr[p]) | ((uint)f2bf(dr[p]) << 16);
        const uint2 pk = {u0, u1};
        *(uint2*)&Xb[half][pq * 4 + p][chl] = pk;
      }
    }
    __syncthreads();

    // ---- conv MFMA: 2 mt x 4 nt x 4 ks x hi/lo ----
    f32x4 acc[2][4];
#pragma unroll
    for (int i = 0; i < 2; ++i)
#pragma unroll
      for (int nt = 0; nt < 4; ++nt)
#pragma unroll
        for (int r = 0; r < 4; ++r) acc[i][nt][r] = 0.f;
#pragma unroll
    for (int ks = 0; ks < 4; ++ks) {
      bf16x8 xbf[4];
#pragma unroll
      for (int nt = 0; nt < 4; ++nt)
        xbf[nt] = *(const bf16x8*)&Xb[1][nt * 16 + r15][ks * 32 + q * 8];
#pragma unroll
      for (int mt2 = 0; mt2 < 2; ++mt2)
#pragma unroll
        for (int nt = 0; nt < 4; ++nt) {
          acc[mt2][nt] = __builtin_amdgcn_mfma_f32_16x16x32_bf16(
              wf[mt2][ks][0], xbf[nt], acc[mt2][nt], 0, 0, 0);
          acc[mt2][nt] = __builtin_amdgcn_mfma_f32_16x16x32_bf16(
              wf[mt2][ks][1], xbf[nt], acc[mt2][nt], 0, 0, 0);
        }
    }

    // ---- epilogue: bias + elu+1, km reg-accumulate, Kloc packed write ----
#pragma unroll
    for (int mt2 = 0; mt2 < 2; ++mt2)
#pragma unroll
      for (int nt = 0; nt < 4; ++nt) {
        ushort pk[4];
#pragma unroll
        for (int r = 0; r < 4; ++r) {
          float v = acc[mt2][nt][r] + bias[mt2][r];
          v = (v > 0.f) ? (v + 1.f) : __expf(v);
          kmacc[mt2][r] += v;
          pk[r] = f2bf(v);
        }
        const uint u0 = (uint)pk[0] | ((uint)pk[1] << 16);
        const uint u1 = (uint)pk[2] | ((uint)pk[3] << 16);
        const uint2 pku = {u0, u1};
        *(uint2*)&Kloc[h][nt * 16 + r15][mt2 * 16 + q * 4] = pku;
      }

    // ---- kv einsum: 4 x mfma_32x32x16, A=Kloc, B=V from Xb (wave-local) ----
    const int vhalf = h >> 2;
    const int vchl = (h & 3) * 32 + e;
#pragma unroll
    for (int ks2 = 0; ks2 < 4; ++ks2) {
      bf16x8 ak, bv;
#pragma unroll
      for (int j = 0; j < 8; ++j) {
        const int pos = ks2 * 16 + q5 * 8 + j;
        ak[j] = (short)Kloc[h][pos][e];
        bv[j] = (short)Xb[vhalf][pos][vchl];
      }
      kvacc = __builtin_amdgcn_mfma_f32_32x32x16_bf16(ak, bv, kvacc, 0, 0, 0);
    }
  }

  // ---- write kv7 partial (32x32 C-layout) ----
  float* dst = kv7 + ((size_t)(sev * NB + b) * 8 + h) * 1024;
#pragma unroll
  for (int reg = 0; reg < 16; ++reg) {
    const int row = (reg & 3) + 8 * (reg >> 2) + 4 * q5;
    dst[row * 32 + e] = kvacc[reg];
  }
  // ---- km: shfl-reduce over r15 group, lane r15==0 writes ----
#pragma unroll
  for (int mt2 = 0; mt2 < 2; ++mt2)
#pragma unroll
    for (int r = 0; r < 4; ++r) {
      float s = kmacc[mt2][r];
      s += __shfl_xor(s, 1);
      s += __shfl_xor(s, 2);
      s += __shfl_xor(s, 4);
      s += __shfl_xor(s, 8);
      if (r15 == 0)
        km7[(size_t)(sev * NB + b) * 256 + h * 32 + mt2 * 16 + q * 4 + r] = s;
    }
}

// ---------------------------------------------------------------------------
// Reduce: sum 7 partials, scale by 1/n.
// ---------------------------------------------------------------------------
__global__ void red_kernel(const float* __restrict__ kv7, const float* __restrict__ km7,
                           float* __restrict__ kvF, float* __restrict__ kmF) {
  const int b = blockIdx.x;
  const int t = threadIdx.x;
  for (int i = t; i < 8192; i += 256) {
    float s = 0.f;
#pragma unroll
    for (int sv = 0; sv < SEV; ++sv)
      s += kv7[(size_t)(sv * NB + b) * 8192 + i];
    kvF[(size_t)b * 8192 + i] = s * INV_N;
  }
  {
    float s = 0.f;
#pragma unroll
    for (int sv = 0; sv < SEV; ++sv)
      s += km7[(size_t)(sv * NB + b) * 256 + t];
    kmF[b * 256 + t] = s * INV_N;
  }
}

// ---------------------------------------------------------------------------
// Kernel B: Q-conv via MFMA, num via 16x16x32 MFMA, den f32, f4 stores.
// ---------------------------------------------------------------------------
__global__ __launch_bounds__(512, 2)
void out_kernel(const float* __restrict__ x, const ushort* __restrict__ Wf,
                const float* __restrict__ qk_b, const float* __restrict__ kvF,
                const float* __restrict__ kmF, float* __restrict__ out) {
  const int bid = blockIdx.x;
  const int b = bid & 31, sev = bid >> 5;
  const int t = threadIdx.x;
  const int wave = t >> 6, l = t & 63;
  const int q = l >> 4, r15 = l & 15;
  const int mw = wave & 3, ng = wave >> 2;
  const int h = wave;

  __shared__ ushort Xb[64][136];
  __shared__ ushort QT[64][264];
  __shared__ float denT[8][64];

  bf16x8 wf[4][4][2];
#pragma unroll
  for (int mti = 0; mti < 4; ++mti)
#pragma unroll
    for (int ks = 0; ks < 4; ++ks)
#pragma unroll
      for (int hl = 0; hl < 2; ++hl) {
        const size_t off =
            (size_t)((((hl * 16 + (mw * 4 + mti)) * 4 + ks) * 64 + l)) * 8;
        wf[mti][ks][hl] = *(const bf16x8*)(Wf + off);
      }

  float bias[4][4], kmw[4][4];
#pragma unroll
  for (int mti = 0; mti < 4; ++mti)
#pragma unroll
    for (int r = 0; r < 4; ++r) {
      const int c = (mw * 4 + mti) * 16 + q * 4 + r;
      bias[mti][r] = qk_b[c];
      kmw[mti][r] = kmF[b * 256 + c];
    }

  bf16x8 bkv[2];
#pragma unroll
  for (int eh = 0; eh < 2; ++eh) {
#pragma unroll
    for (int j = 0; j < 8; ++j)
      bkv[eh][j] = (short)f2bf(
          kvF[(size_t)b * 8192 + h * 1024 + (q * 8 + j) * 32 + eh * 16 + r15]);
  }

  const float* xq = x + (size_t)(b * NCH) * NPIX + sev * 448;

  for (int st = 0; st < SEV; ++st) {
    const int pos0 = st * 64;
#pragma unroll
    for (int rr = 0; rr < 4; ++rr) {
      const int id = t + 512 * rr;
      const int ch = id >> 4;
      const int p4 = (id & 15) * 4;
      const float4 v = *(const float4*)(xq + (size_t)ch * NPIX + pos0 + p4);
      Xb[p4 + 0][ch] = f2bf(v.x);
      Xb[p4 + 1][ch] = f2bf(v.y);
      Xb[p4 + 2][ch] = f2bf(v.z);
      Xb[p4 + 3][ch] = f2bf(v.w);
    }
    __syncthreads();

    f32x4 acc[4][2];
#pragma unroll
    for (int i = 0; i < 4; ++i)
#pragma unroll
      for (int nt = 0; nt < 2; ++nt)
#pragma unroll
        for (int r = 0; r < 4; ++r) acc[i][nt][r] = 0.f;
#pragma unroll
    for (int ks = 0; ks < 4; ++ks) {
      const bf16x8 xb0 = *(const bf16x8*)&Xb[(ng * 2 + 0) * 16 + r15][ks * 32 + q * 8];
      const bf16x8 xb1 = *(const bf16x8*)&Xb[(ng * 2 + 1) * 16 + r15][ks * 32 + q * 8];
#pragma unroll
      for (int mti = 0; mti < 4; ++mti) {
        acc[mti][0] = __builtin_amdgcn_mfma_f32_16x16x32_bf16(wf[mti][ks][0], xb0, acc[mti][0], 0, 0, 0);
        acc[mti][0] = __builtin_amdgcn_mfma_f32_16x16x32_bf16(wf[mti][ks][1], xb0, acc[mti][0], 0, 0, 0);
        acc[mti][1] = __builtin_amdgcn_mfma_f32_16x16x32_bf16(wf[mti][ks][0], xb1, acc[mti][1], 0, 0, 0);
        acc[mti][1] = __builtin_amdgcn_mfma_f32_16x16x32_bf16(wf[mti][ks][1], xb1, acc[mti][1], 0, 0, 0);
      }
    }

    float pdh[2][2];
    pdh[0][0] = pdh[0][1] = pdh[1][0] = pdh[1][1] = 0.f;
#pragma unroll
    for (int mti = 0; mti < 4; ++mti) {
#pragma unroll
      for (int nt = 0; nt < 2; ++nt) {
        ushort pk[4];
        float dsum = 0.f;
#pragma unroll
        for (int r = 0; r < 4; ++r) {
          float v = acc[mti][nt][r] + bias[mti][r];
          v = (v > 0.f) ? (v + 1.f) : __expf(v);
          pk[r] = f2bf(v);
          dsum += v * kmw[mti][r];
        }
        *(uint2*)&QT[(ng * 2 + nt) * 16 + r15][(mw * 4 + mti) * 16 + q * 4] =
            *(const uint2*)pk;
        pdh[mti >> 1][nt] += dsum;
      }
    }
#pragma unroll
    for (int ht = 0; ht < 2; ++ht)
#pragma unroll
      for (int nt = 0; nt < 2; ++nt) {
        float s = pdh[ht][nt];
        s += __shfl_xor(s, 16);
        s += __shfl_xor(s, 32);
        if (q == 0) denT[mw * 2 + ht][(ng * 2 + nt) * 16 + r15] = s;
      }
    __syncthreads();

#pragma unroll
    for (int pt = 0; pt < 4; ++pt) {
      const bf16x8 aq = *(const bf16x8*)&QT[pt * 16 + r15][h * 32 + q * 8];
      f32x4 z;
      z[0] = z[1] = z[2] = z[3] = 0.f;
      const f32x4 n0 = __builtin_amdgcn_mfma_f32_16x16x32_bf16(aq, bkv[0], z, 0, 0, 0);
      const f32x4 n1 = __builtin_amdgcn_mfma_f32_16x16x32_bf16(aq, bkv[1], z, 0, 0, 0);
      float4 o0, o1;
      float rdn[4];
#pragma unroll
      for (int r = 0; r < 4; ++r)
        rdn[r] = 1.0f / (denT[h][pt * 16 + q * 4 + r] + 1e-6f);
      o0.x = n0[0] * rdn[0]; o0.y = n0[1] * rdn[1];
      o0.z = n0[2] * rdn[2]; o0.w = n0[3] * rdn[3];
      o1.x = n1[0] * rdn[0]; o1.y = n1[1] * rdn[1];
      o1.z = n1[2] * rdn[2]; o1.w = n1[3] * rdn[3];
      const int posg = sev * 448 + pos0 + pt * 16 + q * 4;
      const int c0 = h * 32 + r15;
      const int c1 = h * 32 + 16 + r15;
      *(float4*)(out + ((size_t)(b * NCH + c0)) * NPIX + posg) = o0;
      *(float4*)(out + ((size_t)(b * NCH + c1)) * NPIX + posg) = o1;
    }
  }
}

// ---------------------------------------------------------------------------
// Kernel C: depthwise 3x3 pe conv, added into out (RMW).
// 512 threads: wave = (channel 0..3, row-half 0..1) -> 24 waves/CU.
// ---------------------------------------------------------------------------
__global__ __launch_bounds__(512, 4)
void pe_kernel(const float* __restrict__ x, const float* __restrict__ pe_w,
               const float* __restrict__ pe_b, float* __restrict__ out) {
  const int b = blockIdx.y;
  const int c0 = blockIdx.x * 4;
  const int t = threadIdx.x;
  const int wave = t >> 6;
  const int cl = wave & 3;      // channel within block
  const int rh = wave >> 2;     // row half: rows rh*28 .. +28
  const int lane = t & 63;      // lane -> column (56 active)

  __shared__ float xs[4][NPIX];   // 50 KB

  // stage 4 channel images, coalesced float4
#pragma unroll
  for (int cc = 0; cc < 4; ++cc) {
    const float4* src = (const float4*)(x + ((size_t)(b * NCH + c0 + cc)) * NPIX);
    float4* dst = (float4*)&xs[cc][0];
    for (int i = t; i < NPIX / 4; i += 512) dst[i] = src[i];
  }
  __syncthreads();

  const int c = c0 + cl;
  float pw[9];
#pragma unroll
  for (int i = 0; i < 9; ++i) pw[i] = pe_w[c * 9 + i];
  const float pb = pe_b[c];
  float* oc = out + ((size_t)(b * NCH + c)) * NPIX;
  const float* xc = xs[cl];

  if (lane < 56) {
    const bool hasL = (lane > 0), hasR = (lane < 55);
    for (int rg = 0; rg < 7; ++rg) {
      const int rbase = rh * 28 + rg * 4;
      float o[4];
#pragma unroll
      for (int k = 0; k < 4; ++k) o[k] = oc[(rbase + k) * 56 + lane];
#pragma unroll
      for (int k = 0; k < 4; ++k) {
        const int r = rbase + k;
        float s = pb;
#pragma unroll
        for (int dy = -1; dy <= 1; ++dy) {
          const int rr = r + dy;
          if (rr < 0 || rr >= 56) continue;   // wave-uniform
          const float* xrow = xc + rr * 56 + lane;
          if (hasL) s += pw[(dy + 1) * 3 + 0] * xrow[-1];
          s += pw[(dy + 1) * 3 + 1] * xrow[0];
          if (hasR) s += pw[(dy + 1) * 3 + 2] * xrow[1];
        }
        o[k] += s;
      }
#pragma unroll
      for (int k = 0; k < 4; ++k) oc[(rbase + k) * 56 + lane] = o[k];
    }
  }
}

extern "C" void kernel_launch(void* const* d_in, const int* in_sizes, int n_in,
                              void* d_out, int out_size, void* d_ws,
                              size_t ws_size, hipStream_t stream) {
  const float* x    = (const float*)d_in[0];
  const float* qk_w = (const float*)d_in[1];
  const float* qk_b = (const float*)d_in[2];
  const float* pe_w = (const float*)d_in[3];
  const float* pe_b = (const float*)d_in[4];
  float* out = (float*)d_out;

  float* wsf = (float*)d_ws;
  float* kv7 = wsf;
  float* km7 = wsf + KM7_OFF;
  float* kvF = wsf + KVF_OFF;
  float* kmF = wsf + KMF_OFF;
  ushort* Wf = (ushort*)(wsf + WF_OFF);

  wfrag_kernel<<<32, 512, 0, stream>>>(qk_w, Wf);
  kv_kernel<<<SEV * NB, 512, 0, stream>>>(x, Wf, qk_b, kv7, km7);
  red_kernel<<<NB, 256, 0, stream>>>(kv7, km7, kvF, kmF);
  out_kernel<<<SEV * NB, 512, 0, stream>>>(x, Wf, qk_b, kvF, kmF, out);

  dim3 g3(64, NB);
  pe_kernel<<<g3, 512, 0, stream>>>(x, pe_w, pe_b, out);
}